// Round 1
// baseline (1899.374 us; speedup 1.0000x reference)
//
#include <hip/hip_runtime.h>
#include <cmath>

#define TPB 256
#define BN 64
#define BM 128
#define BK 16

// ---------------------------------------------------------------------------
// Scatter-add: edge_sum[dst[e]][c] += edge_attr[e][c]
// One thread per (edge, 4-channel group): float4 load + 4 fp32 atomics.
// ---------------------------------------------------------------------------
__global__ __launch_bounds__(256)
void scatter_add_kernel(const float* __restrict__ edge_attr,
                        const int* __restrict__ dst_idx,
                        float* __restrict__ edge_sum,
                        int n_items)
{
    int idx = blockIdx.x * TPB + threadIdx.x;
    if (idx >= n_items) return;
    int e  = idx >> 5;          // edge id
    int c4 = (idx & 31) << 2;   // channel base (0,4,...,124)
    int dst = dst_idx[e];
    const float4 v = *reinterpret_cast<const float4*>(&edge_attr[(size_t)e * 128 + c4]);
    float* p = &edge_sum[(size_t)dst * 128 + c4];
    atomicAdd(p + 0, v.x);
    atomicAdd(p + 1, v.y);
    atomicAdd(p + 2, v.z);
    atomicAdd(p + 3, v.w);
}

// ---------------------------------------------------------------------------
// Tiled fp32 GEMM + bias + optional ELU.
// C[N x 128] = A[N x K] @ W[K x 128] + bias
// A is optionally the concat [A0 | A1] (each N x 128) when A1 != nullptr.
// Block: 256 threads, tile 64 rows x 128 cols (full M per block -> a row
// is owned by exactly one block, so in-place h update across layers is safe).
// Each thread computes a 4x8 micro-tile.
// ---------------------------------------------------------------------------
__global__ __launch_bounds__(256)
void gemm_bias_act_kernel(const float* __restrict__ A0,
                          const float* __restrict__ A1,   // non-null => K = 256 concat
                          const float* __restrict__ W,    // [K][128] row-major
                          const float* __restrict__ bias, // [128]
                          float* __restrict__ out,        // [N][128]
                          int N, int K, int act)
{
    __shared__ float Ast[BK][BN + 4];   // A tile, transposed (k-major)
    __shared__ float Ws[BK][BM + 4];    // W tile

    const int t = threadIdx.x;
    const int block_row = blockIdx.x * BN;
    const int tx = t & 15;   // col group: cols tx*8 .. tx*8+7
    const int ty = t >> 4;   // row group: rows ty*4 .. ty*4+3

    float acc[4][8];
    #pragma unroll
    for (int i = 0; i < 4; ++i)
        #pragma unroll
        for (int j = 0; j < 8; ++j) acc[i][j] = 0.f;

    const int lr = t >> 2;          // A-load row within tile (0..63)
    const int lk = (t & 3) << 2;    // A-load k offset (0,4,8,12)
    const int wr = t >> 5;          // W-load k row (0..7)
    const int wc = (t & 31) << 2;   // W-load col (0..124)

    for (int k0 = 0; k0 < K; k0 += BK) {
        // --- stage A tile (64 x 16), store transposed ---
        {
            int row = block_row + lr;
            if (row >= N) row = N - 1;          // clamp: garbage rows never stored
            int kk = k0 + lk;
            float4 v;
            if (A1) {
                v = (kk < 128)
                    ? *reinterpret_cast<const float4*>(&A0[(size_t)row * 128 + kk])
                    : *reinterpret_cast<const float4*>(&A1[(size_t)row * 128 + (kk - 128)]);
            } else {
                v = *reinterpret_cast<const float4*>(&A0[(size_t)row * K + kk]);
            }
            Ast[lk + 0][lr] = v.x;
            Ast[lk + 1][lr] = v.y;
            Ast[lk + 2][lr] = v.z;
            Ast[lk + 3][lr] = v.w;
        }
        // --- stage W tile (16 x 128) ---
        {
            *reinterpret_cast<float4*>(&Ws[wr][wc]) =
                *reinterpret_cast<const float4*>(&W[(size_t)(k0 + wr) * 128 + wc]);
            *reinterpret_cast<float4*>(&Ws[wr + 8][wc]) =
                *reinterpret_cast<const float4*>(&W[(size_t)(k0 + wr + 8) * 128 + wc]);
        }
        __syncthreads();

        #pragma unroll
        for (int kk = 0; kk < BK; ++kk) {
            float4 a  = *reinterpret_cast<const float4*>(&Ast[kk][ty * 4]);
            float4 w0 = *reinterpret_cast<const float4*>(&Ws[kk][tx * 8]);
            float4 w1 = *reinterpret_cast<const float4*>(&Ws[kk][tx * 8 + 4]);
            float av[4] = {a.x, a.y, a.z, a.w};
            float wv[8] = {w0.x, w0.y, w0.z, w0.w, w1.x, w1.y, w1.z, w1.w};
            #pragma unroll
            for (int i = 0; i < 4; ++i)
                #pragma unroll
                for (int j = 0; j < 8; ++j)
                    acc[i][j] = fmaf(av[i], wv[j], acc[i][j]);
        }
        __syncthreads();
    }

    // --- epilogue: bias + optional ELU + store ---
    #pragma unroll
    for (int i = 0; i < 4; ++i) {
        int row = block_row + ty * 4 + i;
        if (row >= N) continue;
        #pragma unroll
        for (int j = 0; j < 8; ++j) {
            int col = tx * 8 + j;
            float v = acc[i][j] + bias[col];
            if (act) v = (v > 0.f) ? v : (__expf(v) - 1.f);
            out[(size_t)row * 128 + col] = v;
        }
    }
}

extern "C" void kernel_launch(void* const* d_in, const int* in_sizes, int n_in,
                              void* d_out, int out_size, void* d_ws, size_t ws_size,
                              hipStream_t stream)
{
    const float* x     = (const float*)d_in[0];
    const int*   eidx  = (const int*)d_in[1];   // [2 x E]; row 0 = dst (segment ids)
    const float* eattr = (const float*)d_in[2]; // [E x 128]
    const float* W0 = (const float*)d_in[3];
    const float* b0 = (const float*)d_in[4];
    const float* W2 = (const float*)d_in[5];
    const float* b2 = (const float*)d_in[6];
    const float* W3 = (const float*)d_in[7];
    const float* b3 = (const float*)d_in[8];
    float* out = (float*)d_out;

    const int N = in_sizes[0] / 128;   // 50000
    const int E = in_sizes[2] / 128;   // 800000

    float* edge_sum = (float*)d_ws;                       // [N x 128]
    float* h        = edge_sum + (size_t)N * 128;         // [N x 128], reused for both hidden layers

    // edge_sum must be zeroed every call (ws is poisoned before each launch)
    hipMemsetAsync(edge_sum, 0, (size_t)N * 128 * sizeof(float), stream);

    // 1) segment-sum via atomics
    {
        int n_items = E * 32;   // (edge, 4-channel group)
        int blocks = (n_items + TPB - 1) / TPB;
        scatter_add_kernel<<<blocks, TPB, 0, stream>>>(eattr, eidx, edge_sum, n_items);
    }

    // 2) MLP: elu([x|edge_sum]@W0+b0) -> elu(h@W2+b2) -> h@W3+b3
    int gblocks = (N + BN - 1) / BN;
    gemm_bias_act_kernel<<<gblocks, TPB, 0, stream>>>(x, edge_sum, W0, b0, h,   N, 256, 1);
    gemm_bias_act_kernel<<<gblocks, TPB, 0, stream>>>(h, nullptr,  W2, b2, h,   N, 128, 1);
    gemm_bias_act_kernel<<<gblocks, TPB, 0, stream>>>(h, nullptr,  W3, b3, out, N, 128, 0);
}

// Round 2
// 898.507 us; speedup vs baseline: 2.1139x; 2.1139x over previous
//
#include <hip/hip_runtime.h>
#include <cmath>

#define TPB 256
#define BN 64
#define BM 128
#define BK 16

// ---------------------------------------------------------------------------
// Phase 1: counting sort of edges by destination node.
// ---------------------------------------------------------------------------
__global__ __launch_bounds__(256)
void hist_kernel(const int* __restrict__ dst, int* __restrict__ counts, int E)
{
    int e = blockIdx.x * 256 + threadIdx.x;
    if (e < E) atomicAdd(&counts[dst[e]], 1);
}

// Single-block exclusive scan over N counts -> offsets[0..N], and seed cursor.
__global__ __launch_bounds__(1024)
void scan_kernel(const int* __restrict__ counts, int* __restrict__ offsets,
                 int* __restrict__ cursor, int N, int E)
{
    __shared__ int partial[1024];
    const int t = threadIdx.x;
    const int chunk = (N + 1023) >> 10;
    const int lo = t * chunk;
    const int hi = (lo + chunk < N) ? lo + chunk : N;

    int s = 0;
    for (int i = lo; i < hi; ++i) s += counts[i];
    partial[t] = s;
    __syncthreads();
    // Hillis-Steele inclusive scan
    for (int d = 1; d < 1024; d <<= 1) {
        int v = (t >= d) ? partial[t - d] : 0;
        __syncthreads();
        partial[t] += v;
        __syncthreads();
    }
    int run = (t == 0) ? 0 : partial[t - 1];
    for (int i = lo; i < hi; ++i) {
        int c = counts[i];
        offsets[i] = run;
        cursor[i]  = run;
        run += c;
    }
    if (t == 1023) offsets[N] = run;   // == E
}

__global__ __launch_bounds__(256)
void scatter_perm_kernel(const int* __restrict__ dst, int* __restrict__ cursor,
                         int* __restrict__ perm, int E)
{
    int e = blockIdx.x * 256 + threadIdx.x;
    if (e < E) {
        int p = atomicAdd(&cursor[dst[e]], 1);
        perm[p] = e;
    }
}

// One wave per node: sum its (sorted-contiguous) edges' attr rows.
// Lane l holds channels 2l, 2l+1 -> one coalesced 512B load per edge row.
__global__ __launch_bounds__(256)
void gather_sum_kernel(const float* __restrict__ edge_attr,
                       const int* __restrict__ perm,
                       const int* __restrict__ offsets,
                       float* __restrict__ edge_sum, int N)
{
    const int wid  = (blockIdx.x * 256 + threadIdx.x) >> 6;   // node id
    const int lane = threadIdx.x & 63;
    if (wid >= N) return;
    const int beg = offsets[wid];
    const int end = offsets[wid + 1];

    float2 acc = make_float2(0.f, 0.f);
    for (int base = beg; base < end; base += 64) {
        const int m = (end - base < 64) ? (end - base) : 64;
        int eid = 0;
        if (lane < m) eid = perm[base + lane];
        #pragma unroll 4
        for (int j = 0; j < m; ++j) {
            const int e = __shfl(eid, j, 64);
            const float2 v = *reinterpret_cast<const float2*>(
                &edge_attr[(size_t)e * 128 + lane * 2]);
            acc.x += v.x;
            acc.y += v.y;
        }
    }
    *reinterpret_cast<float2*>(&edge_sum[(size_t)wid * 128 + lane * 2]) = acc;
}

// ---------------------------------------------------------------------------
// Tiled fp32 GEMM + bias + optional ELU (unchanged from R1 as control).
// C[N x 128] = A[N x K] @ W[K x 128] + bias; A = [A0|A1] concat when A1 set.
// ---------------------------------------------------------------------------
__global__ __launch_bounds__(256)
void gemm_bias_act_kernel(const float* __restrict__ A0,
                          const float* __restrict__ A1,
                          const float* __restrict__ W,
                          const float* __restrict__ bias,
                          float* __restrict__ out,
                          int N, int K, int act)
{
    __shared__ float Ast[BK][BN + 4];
    __shared__ float Ws[BK][BM + 4];

    const int t = threadIdx.x;
    const int block_row = blockIdx.x * BN;
    const int tx = t & 15;
    const int ty = t >> 4;

    float acc[4][8];
    #pragma unroll
    for (int i = 0; i < 4; ++i)
        #pragma unroll
        for (int j = 0; j < 8; ++j) acc[i][j] = 0.f;

    const int lr = t >> 2;
    const int lk = (t & 3) << 2;
    const int wr = t >> 5;
    const int wc = (t & 31) << 2;

    for (int k0 = 0; k0 < K; k0 += BK) {
        {
            int row = block_row + lr;
            if (row >= N) row = N - 1;
            int kk = k0 + lk;
            float4 v;
            if (A1) {
                v = (kk < 128)
                    ? *reinterpret_cast<const float4*>(&A0[(size_t)row * 128 + kk])
                    : *reinterpret_cast<const float4*>(&A1[(size_t)row * 128 + (kk - 128)]);
            } else {
                v = *reinterpret_cast<const float4*>(&A0[(size_t)row * K + kk]);
            }
            Ast[lk + 0][lr] = v.x;
            Ast[lk + 1][lr] = v.y;
            Ast[lk + 2][lr] = v.z;
            Ast[lk + 3][lr] = v.w;
        }
        {
            *reinterpret_cast<float4*>(&Ws[wr][wc]) =
                *reinterpret_cast<const float4*>(&W[(size_t)(k0 + wr) * 128 + wc]);
            *reinterpret_cast<float4*>(&Ws[wr + 8][wc]) =
                *reinterpret_cast<const float4*>(&W[(size_t)(k0 + wr + 8) * 128 + wc]);
        }
        __syncthreads();

        #pragma unroll
        for (int kk = 0; kk < BK; ++kk) {
            float4 a  = *reinterpret_cast<const float4*>(&Ast[kk][ty * 4]);
            float4 w0 = *reinterpret_cast<const float4*>(&Ws[kk][tx * 8]);
            float4 w1 = *reinterpret_cast<const float4*>(&Ws[kk][tx * 8 + 4]);
            float av[4] = {a.x, a.y, a.z, a.w};
            float wv[8] = {w0.x, w0.y, w0.z, w0.w, w1.x, w1.y, w1.z, w1.w};
            #pragma unroll
            for (int i = 0; i < 4; ++i)
                #pragma unroll
                for (int j = 0; j < 8; ++j)
                    acc[i][j] = fmaf(av[i], wv[j], acc[i][j]);
        }
        __syncthreads();
    }

    #pragma unroll
    for (int i = 0; i < 4; ++i) {
        int row = block_row + ty * 4 + i;
        if (row >= N) continue;
        #pragma unroll
        for (int j = 0; j < 8; ++j) {
            int col = tx * 8 + j;
            float v = acc[i][j] + bias[col];
            if (act) v = (v > 0.f) ? v : (__expf(v) - 1.f);
            out[(size_t)row * 128 + col] = v;
        }
    }
}

extern "C" void kernel_launch(void* const* d_in, const int* in_sizes, int n_in,
                              void* d_out, int out_size, void* d_ws, size_t ws_size,
                              hipStream_t stream)
{
    const float* x     = (const float*)d_in[0];
    const int*   eidx  = (const int*)d_in[1];   // row 0 = dst (segment ids)
    const float* eattr = (const float*)d_in[2];
    const float* W0 = (const float*)d_in[3];
    const float* b0 = (const float*)d_in[4];
    const float* W2 = (const float*)d_in[5];
    const float* b2 = (const float*)d_in[6];
    const float* W3 = (const float*)d_in[7];
    const float* b3 = (const float*)d_in[8];
    float* out = (float*)d_out;

    const int N = in_sizes[0] / 128;   // 50000
    const int E = in_sizes[2] / 128;   // 800000

    // ---- workspace layout ----
    int* counts  = (int*)d_ws;                 // [N]
    int* offsets = counts + N;                 // [N+1]
    int* cursor  = offsets + (N + 1);          // [N]
    int* perm    = cursor + N;                 // [E]
    // align float region to 256B for float4 accesses
    uintptr_t p = (uintptr_t)(perm + E);
    p = (p + 255) & ~(uintptr_t)255;
    float* edge_sum = (float*)p;               // [N*128]
    float* h        = edge_sum + (size_t)N * 128;  // [N*128]

    hipMemsetAsync(counts, 0, (size_t)N * sizeof(int), stream);

    int eblocks = (E + 255) / 256;
    hist_kernel<<<eblocks, 256, 0, stream>>>(eidx, counts, E);
    scan_kernel<<<1, 1024, 0, stream>>>(counts, offsets, cursor, N, E);
    scatter_perm_kernel<<<eblocks, 256, 0, stream>>>(eidx, cursor, perm, E);
    {
        int gthreads = N * 64;
        int gblocks = (gthreads + 255) / 256;
        gather_sum_kernel<<<gblocks, 256, 0, stream>>>(eattr, perm, offsets, edge_sum, N);
    }

    int gblocks = (N + BN - 1) / BN;
    gemm_bias_act_kernel<<<gblocks, TPB, 0, stream>>>(x, edge_sum, W0, b0, h,   N, 256, 1);
    gemm_bias_act_kernel<<<gblocks, TPB, 0, stream>>>(h, nullptr,  W2, b2, h,   N, 128, 1);
    gemm_bias_act_kernel<<<gblocks, TPB, 0, stream>>>(h, nullptr,  W3, b3, out, N, 128, 0);
}

// Round 3
// 838.764 us; speedup vs baseline: 2.2645x; 1.0712x over previous
//
#include <hip/hip_runtime.h>
#include <cmath>

typedef __attribute__((ext_vector_type(8))) short bf16x8;
typedef __attribute__((ext_vector_type(4))) float f32x4;

__device__ __forceinline__ short f2bf(float f) {
    unsigned u = __builtin_bit_cast(unsigned, f);
    u += 0x7fff + ((u >> 16) & 1);   // RNE
    return (short)(u >> 16);
}

// ---------------------------------------------------------------------------
// Counting sort of edges by destination (unchanged from R2).
// ---------------------------------------------------------------------------
__global__ __launch_bounds__(256)
void hist_kernel(const int* __restrict__ dst, int* __restrict__ counts, int E)
{
    int e = blockIdx.x * 256 + threadIdx.x;
    if (e < E) atomicAdd(&counts[dst[e]], 1);
}

__global__ __launch_bounds__(1024)
void scan_kernel(const int* __restrict__ counts, int* __restrict__ offsets,
                 int* __restrict__ cursor, int N, int E)
{
    __shared__ int partial[1024];
    const int t = threadIdx.x;
    const int chunk = (N + 1023) >> 10;
    const int lo = t * chunk;
    const int hi = (lo + chunk < N) ? lo + chunk : N;

    int s = 0;
    for (int i = lo; i < hi; ++i) s += counts[i];
    partial[t] = s;
    __syncthreads();
    for (int d = 1; d < 1024; d <<= 1) {
        int v = (t >= d) ? partial[t - d] : 0;
        __syncthreads();
        partial[t] += v;
        __syncthreads();
    }
    int run = (t == 0) ? 0 : partial[t - 1];
    for (int i = lo; i < hi; ++i) {
        int c = counts[i];
        offsets[i] = run;
        cursor[i]  = run;
        run += c;
    }
    if (t == 1023) offsets[N] = run;
}

__global__ __launch_bounds__(256)
void scatter_perm_kernel(const int* __restrict__ dst, int* __restrict__ cursor,
                         int* __restrict__ perm, int E)
{
    int e = blockIdx.x * 256 + threadIdx.x;
    if (e < E) {
        int p = atomicAdd(&cursor[dst[e]], 1);
        perm[p] = e;
    }
}

__global__ __launch_bounds__(256)
void gather_sum_kernel(const float* __restrict__ edge_attr,
                       const int* __restrict__ perm,
                       const int* __restrict__ offsets,
                       float* __restrict__ edge_sum, int N)
{
    const int wid  = (blockIdx.x * 256 + threadIdx.x) >> 6;
    const int lane = threadIdx.x & 63;
    if (wid >= N) return;
    const int beg = offsets[wid];
    const int end = offsets[wid + 1];

    float2 acc = make_float2(0.f, 0.f);
    for (int base = beg; base < end; base += 64) {
        const int m = (end - base < 64) ? (end - base) : 64;
        int eid = 0;
        if (lane < m) eid = perm[base + lane];
        #pragma unroll 4
        for (int j = 0; j < m; ++j) {
            const int e = __shfl(eid, j, 64);
            const float2 v = *reinterpret_cast<const float2*>(
                &edge_attr[(size_t)e * 128 + lane * 2]);
            acc.x += v.x;
            acc.y += v.y;
        }
    }
    *reinterpret_cast<float2*>(&edge_sum[(size_t)wid * 128 + lane * 2]) = acc;
}

// ---------------------------------------------------------------------------
// Fused 3-layer MLP, bf16 MFMA, 128 rows per block, 512 threads (8 waves).
// LDS: At (128x128 bf16, XOR-swizzled) + Wt (W^T, 128n x 128k bf16, swizzled).
// Layer0 K=256 split into two K=128 halves (x | edge_sum), acc in registers.
// Swizzle: element (row, k) stored at row*128 + ((k>>3) ^ (row&15))*8 + (k&7)
// -> fragment reads are 16B ds_read_b128, 2-way-max bank aliasing (free).
// ---------------------------------------------------------------------------
__device__ __forceinline__ void stage_W(const float* __restrict__ W, int krow0,
                                        short* __restrict__ Wt, int tid)
{
    #pragma unroll
    for (int i = 0; i < 16; ++i) {
        int p = tid + i * 512;
        int n = p & 127;
        int k = (p >> 7) << 1;
        float a = W[(size_t)(krow0 + k) * 128 + n];
        float b = W[(size_t)(krow0 + k + 1) * 128 + n];
        int grp = (k >> 3) ^ (n & 15);
        ushort2 s;
        s.x = (unsigned short)f2bf(a);
        s.y = (unsigned short)f2bf(b);
        *reinterpret_cast<ushort2*>(&Wt[n * 128 + grp * 8 + (k & 7)]) = s;
    }
}

__global__ __launch_bounds__(512, 2)
void fused_mlp_kernel(const float* __restrict__ x,
                      const float* __restrict__ edge_sum,
                      const float* __restrict__ W0, const float* __restrict__ b0,
                      const float* __restrict__ W2, const float* __restrict__ b2,
                      const float* __restrict__ W3, const float* __restrict__ b3,
                      float* __restrict__ out, int N)
{
    __shared__ short At[128 * 128];
    __shared__ short Wt[128 * 128];

    const int tid  = threadIdx.x;
    const int lane = tid & 63;
    const int wv   = tid >> 6;        // wave 0..7
    const int l15  = lane & 15;
    const int quad = lane >> 4;
    const int m0   = wv * 16;         // 16 rows per wave
    const int blockRow = blockIdx.x * 128;

    f32x4 acc[8];
    #pragma unroll
    for (int nt = 0; nt < 8; ++nt) acc[nt] = (f32x4){0.f, 0.f, 0.f, 0.f};

    // ---------------- layer 0: two K-halves ----------------
    for (int half = 0; half < 2; ++half) {
        const float* Asrc = half ? edge_sum : x;
        __syncthreads();   // previous half's LDS reads complete
        // stage A half (128 rows x 128 cols fp32 -> bf16)
        #pragma unroll
        for (int i = 0; i < 8; ++i) {
            int f  = tid + i * 512;
            int r  = f >> 5;
            int c4 = (f & 31) << 2;
            int g  = blockRow + r; if (g >= N) g = N - 1;
            const float4 v = *reinterpret_cast<const float4*>(&Asrc[(size_t)g * 128 + c4]);
            int grp = (c4 >> 3) ^ (r & 15);
            ushort4 s;
            s.x = (unsigned short)f2bf(v.x);
            s.y = (unsigned short)f2bf(v.y);
            s.z = (unsigned short)f2bf(v.z);
            s.w = (unsigned short)f2bf(v.w);
            *reinterpret_cast<ushort4*>(&At[r * 128 + grp * 8 + (c4 & 7)]) = s;
        }
        stage_W(W0, half * 128, Wt, tid);
        __syncthreads();
        #pragma unroll
        for (int ks = 0; ks < 4; ++ks) {
            int g = ks * 4 + quad;
            int so = ((g ^ l15) << 3);
            bf16x8 a = *reinterpret_cast<bf16x8*>(&At[(m0 + l15) * 128 + so]);
            #pragma unroll
            for (int nt = 0; nt < 8; ++nt) {
                bf16x8 b = *reinterpret_cast<bf16x8*>(&Wt[(nt * 16 + l15) * 128 + so]);
                acc[nt] = __builtin_amdgcn_mfma_f32_16x16x32_bf16(a, b, acc[nt], 0, 0, 0);
            }
        }
    }

    // ---------------- epilogue 0 -> h in At; stage W2 ----------------
    __syncthreads();
    #pragma unroll
    for (int nt = 0; nt < 8; ++nt) {
        float bv = b0[nt * 16 + l15];
        #pragma unroll
        for (int r = 0; r < 4; ++r) {
            float v = acc[nt][r] + bv;
            v = (v > 0.f) ? v : (__expf(v) - 1.f);
            int m = m0 + quad * 4 + r;
            int c = nt * 16 + l15;
            int grp = (c >> 3) ^ (m & 15);
            At[m * 128 + grp * 8 + (c & 7)] = f2bf(v);
        }
        acc[nt] = (f32x4){0.f, 0.f, 0.f, 0.f};
    }
    stage_W(W2, 0, Wt, tid);
    __syncthreads();

    // ---------------- layer 1 ----------------
    #pragma unroll
    for (int ks = 0; ks < 4; ++ks) {
        int g = ks * 4 + quad;
        int so = ((g ^ l15) << 3);
        bf16x8 a = *reinterpret_cast<bf16x8*>(&At[(m0 + l15) * 128 + so]);
        #pragma unroll
        for (int nt = 0; nt < 8; ++nt) {
            bf16x8 b = *reinterpret_cast<bf16x8*>(&Wt[(nt * 16 + l15) * 128 + so]);
            acc[nt] = __builtin_amdgcn_mfma_f32_16x16x32_bf16(a, b, acc[nt], 0, 0, 0);
        }
    }

    // ---------------- epilogue 1 -> h2 in At; stage W3 ----------------
    __syncthreads();
    #pragma unroll
    for (int nt = 0; nt < 8; ++nt) {
        float bv = b2[nt * 16 + l15];
        #pragma unroll
        for (int r = 0; r < 4; ++r) {
            float v = acc[nt][r] + bv;
            v = (v > 0.f) ? v : (__expf(v) - 1.f);
            int m = m0 + quad * 4 + r;
            int c = nt * 16 + l15;
            int grp = (c >> 3) ^ (m & 15);
            At[m * 128 + grp * 8 + (c & 7)] = f2bf(v);
        }
        acc[nt] = (f32x4){0.f, 0.f, 0.f, 0.f};
    }
    stage_W(W3, 0, Wt, tid);
    __syncthreads();

    // ---------------- layer 2 ----------------
    #pragma unroll
    for (int ks = 0; ks < 4; ++ks) {
        int g = ks * 4 + quad;
        int so = ((g ^ l15) << 3);
        bf16x8 a = *reinterpret_cast<bf16x8*>(&At[(m0 + l15) * 128 + so]);
        #pragma unroll
        for (int nt = 0; nt < 8; ++nt) {
            bf16x8 b = *reinterpret_cast<bf16x8*>(&Wt[(nt * 16 + l15) * 128 + so]);
            acc[nt] = __builtin_amdgcn_mfma_f32_16x16x32_bf16(a, b, acc[nt], 0, 0, 0);
        }
    }

    // ---------------- final store ----------------
    #pragma unroll
    for (int nt = 0; nt < 8; ++nt) {
        float bv = b3[nt * 16 + l15];
        #pragma unroll
        for (int r = 0; r < 4; ++r) {
            int gr = blockRow + m0 + quad * 4 + r;
            if (gr < N) out[(size_t)gr * 128 + nt * 16 + l15] = acc[nt][r] + bv;
        }
    }
}

extern "C" void kernel_launch(void* const* d_in, const int* in_sizes, int n_in,
                              void* d_out, int out_size, void* d_ws, size_t ws_size,
                              hipStream_t stream)
{
    const float* x     = (const float*)d_in[0];
    const int*   eidx  = (const int*)d_in[1];   // row 0 = dst
    const float* eattr = (const float*)d_in[2];
    const float* W0 = (const float*)d_in[3];
    const float* b0 = (const float*)d_in[4];
    const float* W2 = (const float*)d_in[5];
    const float* b2 = (const float*)d_in[6];
    const float* W3 = (const float*)d_in[7];
    const float* b3 = (const float*)d_in[8];
    float* out = (float*)d_out;

    const int N = in_sizes[0] / 128;   // 50000
    const int E = in_sizes[2] / 128;   // 800000

    int* counts  = (int*)d_ws;
    int* offsets = counts + N;
    int* cursor  = offsets + (N + 1);
    int* perm    = cursor + N;
    uintptr_t p = (uintptr_t)(perm + E);
    p = (p + 255) & ~(uintptr_t)255;
    float* edge_sum = (float*)p;               // [N*128]

    hipMemsetAsync(counts, 0, (size_t)N * sizeof(int), stream);

    int eblocks = (E + 255) / 256;
    hist_kernel<<<eblocks, 256, 0, stream>>>(eidx, counts, E);
    scan_kernel<<<1, 1024, 0, stream>>>(counts, offsets, cursor, N, E);
    scatter_perm_kernel<<<eblocks, 256, 0, stream>>>(eidx, cursor, perm, E);
    {
        int gthreads = N * 64;
        int gblocks = (gthreads + 255) / 256;
        gather_sum_kernel<<<gblocks, 256, 0, stream>>>(eattr, perm, offsets, edge_sum, N);
    }

    int mblocks = (N + 127) / 128;
    fused_mlp_kernel<<<mblocks, 512, 0, stream>>>(x, edge_sum, W0, b0, W2, b2,
                                                  W3, b3, out, N);
}

// Round 4
// 727.199 us; speedup vs baseline: 2.6119x; 1.1534x over previous
//
#include <hip/hip_runtime.h>
#include <cmath>

typedef __attribute__((ext_vector_type(8))) short bf16x8;
typedef __attribute__((ext_vector_type(4))) float f32x4;

__device__ __forceinline__ short f2bf(float f) {
    unsigned u = __builtin_bit_cast(unsigned, f);
    u += 0x7fff + ((u >> 16) & 1);   // RNE
    return (short)(u >> 16);
}

// ---------------------------------------------------------------------------
// Counting sort of edges by destination.
// ---------------------------------------------------------------------------
__global__ __launch_bounds__(256)
void hist_kernel(const int* __restrict__ dst, int* __restrict__ counts, int E)
{
    int e = blockIdx.x * 256 + threadIdx.x;
    if (e < E) atomicAdd(&counts[dst[e]], 1);
}

// --- coalesced 3-phase scan over N counts -> offsets[0..N] & cursor ---
#define SCAN_B 256

// P1: per-block exclusive scan (into offsets) + per-block total
__global__ __launch_bounds__(SCAN_B)
void scan_p1_kernel(const int* __restrict__ counts, int* __restrict__ offsets,
                    int* __restrict__ blockSums, int N)
{
    __shared__ int sh[SCAN_B];
    const int t = threadIdx.x;
    const int i = blockIdx.x * SCAN_B + t;
    int v = (i < N) ? counts[i] : 0;
    sh[t] = v;
    __syncthreads();
    for (int d = 1; d < SCAN_B; d <<= 1) {
        int u = (t >= d) ? sh[t - d] : 0;
        __syncthreads();
        sh[t] += u;
        __syncthreads();
    }
    if (i < N) offsets[i] = sh[t] - v;           // local exclusive
    if (t == SCAN_B - 1) blockSums[blockIdx.x] = sh[SCAN_B - 1];
}

// P2: single tiny block: exclusive scan of blockSums (nblk <= 256)
__global__ __launch_bounds__(SCAN_B)
void scan_p2_kernel(int* __restrict__ blockSums, int nblk)
{
    __shared__ int sh[SCAN_B];
    const int t = threadIdx.x;
    int v = (t < nblk) ? blockSums[t] : 0;
    sh[t] = v;
    __syncthreads();
    for (int d = 1; d < SCAN_B; d <<= 1) {
        int u = (t >= d) ? sh[t - d] : 0;
        __syncthreads();
        sh[t] += u;
        __syncthreads();
    }
    if (t < nblk) blockSums[t] = sh[t] - v;      // exclusive
}

// P3: add block offset, emit offsets & cursor (coalesced)
__global__ __launch_bounds__(SCAN_B)
void scan_p3_kernel(int* __restrict__ offsets, const int* __restrict__ blockSums,
                    int* __restrict__ cursor, int N, int E)
{
    const int i = blockIdx.x * SCAN_B + threadIdx.x;
    if (i < N) {
        int o = offsets[i] + blockSums[blockIdx.x];
        offsets[i] = o;
        cursor[i]  = o;
    }
    if (i == 0) offsets[N] = E;
}

__global__ __launch_bounds__(256)
void scatter_perm_kernel(const int* __restrict__ dst, int* __restrict__ cursor,
                         int* __restrict__ perm, int E)
{
    int e = blockIdx.x * 256 + threadIdx.x;
    if (e < E) {
        int p = atomicAdd(&cursor[dst[e]], 1);
        perm[p] = e;
    }
}

// ---------------------------------------------------------------------------
// Gather-sum: one wave per node. Wave processes 2 edges per step:
// lanes 0-31 (half=0) hold even edge, lanes 32-63 odd edge; each li covers
// channels 4*li..4*li+3 as float4 (16B/lane). Cross-half shuffle-reduce at end.
// ---------------------------------------------------------------------------
__global__ __launch_bounds__(256)
void gather_sum_kernel(const float* __restrict__ edge_attr,
                       const int* __restrict__ perm,
                       const int* __restrict__ offsets,
                       float* __restrict__ edge_sum, int N)
{
    const int wid  = (blockIdx.x * 256 + threadIdx.x) >> 6;
    const int lane = threadIdx.x & 63;
    if (wid >= N) return;
    const int beg = offsets[wid];
    const int end = offsets[wid + 1];
    const int half = lane >> 5;
    const int li   = lane & 31;

    float4 acc = make_float4(0.f, 0.f, 0.f, 0.f);
    for (int base = beg; base < end; base += 64) {
        const int m = (end - base < 64) ? (end - base) : 64;
        int eid = 0;
        if (lane < m) eid = perm[base + lane];
        const int pairs = (m + 1) >> 1;
        #pragma unroll 4
        for (int j = 0; j < pairs; ++j) {
            const int idx = 2 * j + half;
            const int e = __shfl(eid, idx, 64);
            if (idx < m) {
                const float4 v = *reinterpret_cast<const float4*>(
                    &edge_attr[(size_t)e * 128 + li * 4]);
                acc.x += v.x; acc.y += v.y; acc.z += v.z; acc.w += v.w;
            }
        }
    }
    // fold upper half into lower half, store 512B per node from lanes 0-31
    float4 other;
    other.x = __shfl(acc.x, li + 32, 64);
    other.y = __shfl(acc.y, li + 32, 64);
    other.z = __shfl(acc.z, li + 32, 64);
    other.w = __shfl(acc.w, li + 32, 64);
    if (half == 0) {
        acc.x += other.x; acc.y += other.y; acc.z += other.z; acc.w += other.w;
        *reinterpret_cast<float4*>(&edge_sum[(size_t)wid * 128 + li * 4]) = acc;
    }
}

// ---------------------------------------------------------------------------
// Fused 3-layer MLP, bf16 MFMA (unchanged from R3 as control).
// ---------------------------------------------------------------------------
__device__ __forceinline__ void stage_W(const float* __restrict__ W, int krow0,
                                        short* __restrict__ Wt, int tid)
{
    #pragma unroll
    for (int i = 0; i < 16; ++i) {
        int p = tid + i * 512;
        int n = p & 127;
        int k = (p >> 7) << 1;
        float a = W[(size_t)(krow0 + k) * 128 + n];
        float b = W[(size_t)(krow0 + k + 1) * 128 + n];
        int grp = (k >> 3) ^ (n & 15);
        ushort2 s;
        s.x = (unsigned short)f2bf(a);
        s.y = (unsigned short)f2bf(b);
        *reinterpret_cast<ushort2*>(&Wt[n * 128 + grp * 8 + (k & 7)]) = s;
    }
}

__global__ __launch_bounds__(512, 2)
void fused_mlp_kernel(const float* __restrict__ x,
                      const float* __restrict__ edge_sum,
                      const float* __restrict__ W0, const float* __restrict__ b0,
                      const float* __restrict__ W2, const float* __restrict__ b2,
                      const float* __restrict__ W3, const float* __restrict__ b3,
                      float* __restrict__ out, int N)
{
    __shared__ short At[128 * 128];
    __shared__ short Wt[128 * 128];

    const int tid  = threadIdx.x;
    const int lane = tid & 63;
    const int wv   = tid >> 6;
    const int l15  = lane & 15;
    const int quad = lane >> 4;
    const int m0   = wv * 16;
    const int blockRow = blockIdx.x * 128;

    f32x4 acc[8];
    #pragma unroll
    for (int nt = 0; nt < 8; ++nt) acc[nt] = (f32x4){0.f, 0.f, 0.f, 0.f};

    for (int half = 0; half < 2; ++half) {
        const float* Asrc = half ? edge_sum : x;
        __syncthreads();
        #pragma unroll
        for (int i = 0; i < 8; ++i) {
            int f  = tid + i * 512;
            int r  = f >> 5;
            int c4 = (f & 31) << 2;
            int g  = blockRow + r; if (g >= N) g = N - 1;
            const float4 v = *reinterpret_cast<const float4*>(&Asrc[(size_t)g * 128 + c4]);
            int grp = (c4 >> 3) ^ (r & 15);
            ushort4 s;
            s.x = (unsigned short)f2bf(v.x);
            s.y = (unsigned short)f2bf(v.y);
            s.z = (unsigned short)f2bf(v.z);
            s.w = (unsigned short)f2bf(v.w);
            *reinterpret_cast<ushort4*>(&At[r * 128 + grp * 8 + (c4 & 7)]) = s;
        }
        stage_W(W0, half * 128, Wt, tid);
        __syncthreads();
        #pragma unroll
        for (int ks = 0; ks < 4; ++ks) {
            int g = ks * 4 + quad;
            int so = ((g ^ l15) << 3);
            bf16x8 a = *reinterpret_cast<bf16x8*>(&At[(m0 + l15) * 128 + so]);
            #pragma unroll
            for (int nt = 0; nt < 8; ++nt) {
                bf16x8 b = *reinterpret_cast<bf16x8*>(&Wt[(nt * 16 + l15) * 128 + so]);
                acc[nt] = __builtin_amdgcn_mfma_f32_16x16x32_bf16(a, b, acc[nt], 0, 0, 0);
            }
        }
    }

    __syncthreads();
    #pragma unroll
    for (int nt = 0; nt < 8; ++nt) {
        float bv = b0[nt * 16 + l15];
        #pragma unroll
        for (int r = 0; r < 4; ++r) {
            float v = acc[nt][r] + bv;
            v = (v > 0.f) ? v : (__expf(v) - 1.f);
            int m = m0 + quad * 4 + r;
            int c = nt * 16 + l15;
            int grp = (c >> 3) ^ (m & 15);
            At[m * 128 + grp * 8 + (c & 7)] = f2bf(v);
        }
        acc[nt] = (f32x4){0.f, 0.f, 0.f, 0.f};
    }
    stage_W(W2, 0, Wt, tid);
    __syncthreads();

    #pragma unroll
    for (int ks = 0; ks < 4; ++ks) {
        int g = ks * 4 + quad;
        int so = ((g ^ l15) << 3);
        bf16x8 a = *reinterpret_cast<bf16x8*>(&At[(m0 + l15) * 128 + so]);
        #pragma unroll
        for (int nt = 0; nt < 8; ++nt) {
            bf16x8 b = *reinterpret_cast<bf16x8*>(&Wt[(nt * 16 + l15) * 128 + so]);
            acc[nt] = __builtin_amdgcn_mfma_f32_16x16x32_bf16(a, b, acc[nt], 0, 0, 0);
        }
    }

    __syncthreads();
    #pragma unroll
    for (int nt = 0; nt < 8; ++nt) {
        float bv = b2[nt * 16 + l15];
        #pragma unroll
        for (int r = 0; r < 4; ++r) {
            float v = acc[nt][r] + bv;
            v = (v > 0.f) ? v : (__expf(v) - 1.f);
            int m = m0 + quad * 4 + r;
            int c = nt * 16 + l15;
            int grp = (c >> 3) ^ (m & 15);
            At[m * 128 + grp * 8 + (c & 7)] = f2bf(v);
        }
        acc[nt] = (f32x4){0.f, 0.f, 0.f, 0.f};
    }
    stage_W(W3, 0, Wt, tid);
    __syncthreads();

    #pragma unroll
    for (int ks = 0; ks < 4; ++ks) {
        int g = ks * 4 + quad;
        int so = ((g ^ l15) << 3);
        bf16x8 a = *reinterpret_cast<bf16x8*>(&At[(m0 + l15) * 128 + so]);
        #pragma unroll
        for (int nt = 0; nt < 8; ++nt) {
            bf16x8 b = *reinterpret_cast<bf16x8*>(&Wt[(nt * 16 + l15) * 128 + so]);
            acc[nt] = __builtin_amdgcn_mfma_f32_16x16x32_bf16(a, b, acc[nt], 0, 0, 0);
        }
    }

    #pragma unroll
    for (int nt = 0; nt < 8; ++nt) {
        float bv = b3[nt * 16 + l15];
        #pragma unroll
        for (int r = 0; r < 4; ++r) {
            int gr = blockRow + m0 + quad * 4 + r;
            if (gr < N) out[(size_t)gr * 128 + nt * 16 + l15] = acc[nt][r] + bv;
        }
    }
}

extern "C" void kernel_launch(void* const* d_in, const int* in_sizes, int n_in,
                              void* d_out, int out_size, void* d_ws, size_t ws_size,
                              hipStream_t stream)
{
    const float* x     = (const float*)d_in[0];
    const int*   eidx  = (const int*)d_in[1];   // row 0 = dst
    const float* eattr = (const float*)d_in[2];
    const float* W0 = (const float*)d_in[3];
    const float* b0 = (const float*)d_in[4];
    const float* W2 = (const float*)d_in[5];
    const float* b2 = (const float*)d_in[6];
    const float* W3 = (const float*)d_in[7];
    const float* b3 = (const float*)d_in[8];
    float* out = (float*)d_out;

    const int N = in_sizes[0] / 128;   // 50000
    const int E = in_sizes[2] / 128;   // 800000

    int* counts    = (int*)d_ws;                 // [N]
    int* offsets   = counts + N;                 // [N+1]
    int* cursor    = offsets + (N + 1);          // [N]
    int* blockSums = cursor + N;                 // [<=256]
    int* perm      = blockSums + 256;            // [E]
    uintptr_t p = (uintptr_t)(perm + E);
    p = (p + 255) & ~(uintptr_t)255;
    float* edge_sum = (float*)p;                 // [N*128]

    hipMemsetAsync(counts, 0, (size_t)N * sizeof(int), stream);

    const int eblocks = (E + 255) / 256;
    const int nblk    = (N + SCAN_B - 1) / SCAN_B;   // 196 <= 256

    hist_kernel<<<eblocks, 256, 0, stream>>>(eidx, counts, E);
    scan_p1_kernel<<<nblk, SCAN_B, 0, stream>>>(counts, offsets, blockSums, N);
    scan_p2_kernel<<<1, SCAN_B, 0, stream>>>(blockSums, nblk);
    scan_p3_kernel<<<nblk, SCAN_B, 0, stream>>>(offsets, blockSums, cursor, N, E);
    scatter_perm_kernel<<<eblocks, 256, 0, stream>>>(eidx, cursor, perm, E);
    {
        int gthreads = N * 64;
        int gblocks = (gthreads + 255) / 256;
        gather_sum_kernel<<<gblocks, 256, 0, stream>>>(eattr, perm, offsets, edge_sum, N);
    }

    int mblocks = (N + 127) / 128;
    fused_mlp_kernel<<<mblocks, 512, 0, stream>>>(x, edge_sum, W0, b0, W2, b2,
                                                  W3, b3, out, N);
}